// Round 1
// baseline (483.023 us; speedup 1.0000x reference)
//
#include <hip/hip_runtime.h>

#define TT 512
#define II 10
#define HH 32

__device__ __forceinline__ float frcp(float v) { return __builtin_amdgcn_rcpf(v); }
__device__ __forceinline__ float sigm(float v) { return frcp(1.0f + __expf(-v)); }
__device__ __forceinline__ float tanh_f(float v) { return 1.0f - 2.0f * frcp(__expf(2.0f * v) + 1.0f); }

// Layout: thread = (batch row, hidden unit j). Wave = 2 batch rows x 32 units.
// Block = 256 threads = 8 batch rows; each wave exclusively owns its 2 rows'
// h slots in LDS -> no __syncthreads in the hot loop (LDS ops are in-order
// within a wave). W_hh/W_ih rows live in registers (~172 VGPRs) ->
// __launch_bounds__(256,2) = 2 waves/SIMD, grid 512 blocks = 2 blocks/CU fills it.
extern "C" __global__ __launch_bounds__(256, 2)
void lstm_fused(const float* __restrict__ x,
                const float* __restrict__ h0,
                const float* __restrict__ c0,
                const float* __restrict__ W_ih,
                const float* __restrict__ W_hh,
                const float* __restrict__ b_ih,
                const float* __restrict__ b_hh,
                const float* __restrict__ W_lin,
                const float* __restrict__ b_lin,
                float* __restrict__ out)
{
    __shared__ float h_lds[8][HH];

    const int tid  = threadIdx.x;
    const int wv   = tid >> 6;
    const int lane = tid & 63;
    const int half = lane >> 5;
    const int j    = lane & 31;      // hidden unit owned by this thread
    const int bl   = wv * 2 + half;  // local batch row (0..7)
    const int b    = blockIdx.x * 8 + bl;

    // ---- load weights into registers (one-time; W is 21.5 KB, L1/L2-resident) ----
    float w[4][HH];   // W_hh rows {j, 32+j, 64+j, 96+j}
    float wi[4][II];  // W_ih rows
    float bias[4];    // b_ih + b_hh fused
    #pragma unroll
    for (int g = 0; g < 4; ++g) {
        const int row = g * HH + j;
        const float4* wr = reinterpret_cast<const float4*>(W_hh + row * HH);
        #pragma unroll
        for (int k4 = 0; k4 < HH / 4; ++k4) {
            const float4 v = wr[k4];
            w[g][4 * k4 + 0] = v.x; w[g][4 * k4 + 1] = v.y;
            w[g][4 * k4 + 2] = v.z; w[g][4 * k4 + 3] = v.w;
        }
        const float2* wir = reinterpret_cast<const float2*>(W_ih + row * II);
        #pragma unroll
        for (int i2 = 0; i2 < II / 2; ++i2) {
            const float2 v = wir[i2];
            wi[g][2 * i2 + 0] = v.x; wi[g][2 * i2 + 1] = v.y;
        }
        bias[g] = b_ih[row] + b_hh[row];
    }

    float c = c0[b * HH + j];
    h_lds[bl][j] = h0[b * HH + j];   // same-wave RAW: LDS in-order per wave

    const float* xp = x + (size_t)b * (TT * II);

    // prefetch x[t=0]
    float xv[II];
    {
        const float2* x2 = reinterpret_cast<const float2*>(xp);
        #pragma unroll
        for (int i = 0; i < II / 2; ++i) { const float2 v = x2[i]; xv[2 * i] = v.x; xv[2 * i + 1] = v.y; }
    }

    float hv = 0.0f;
    for (int t = 0; t < TT; ++t) {
        // software-prefetch next step's x (branchless clamp to avoid uninit read)
        float xn[II];
        {
            const int tn = (t + 1 < TT) ? (t + 1) : t;
            const float2* x2 = reinterpret_cast<const float2*>(xp + tn * II);
            #pragma unroll
            for (int i = 0; i < II / 2; ++i) { const float2 v = x2[i]; xn[2 * i] = v.x; xn[2 * i + 1] = v.y; }
        }

        float a0 = bias[0], a1 = bias[1], a2 = bias[2], a3 = bias[3];

        // input projection: 40 FMAs (overlaps the in-flight LDS h reads)
        #pragma unroll
        for (int i = 0; i < II; ++i) {
            const float xi = xv[i];
            a0 += wi[0][i] * xi;
            a1 += wi[1][i] * xi;
            a2 += wi[2][i] * xi;
            a3 += wi[3][i] * xi;
        }

        // recurrent projection: h broadcast from LDS as float4 (same-address
        // within half-wave = broadcast; 2 halves = 2-way alias = free)
        #pragma unroll
        for (int k4 = 0; k4 < HH / 4; ++k4) {
            const float4 h4 = *reinterpret_cast<const float4*>(&h_lds[bl][4 * k4]);
            const float h0v = h4.x, h1v = h4.y, h2v = h4.z, h3v = h4.w;
            a0 += w[0][4 * k4 + 0] * h0v; a1 += w[1][4 * k4 + 0] * h0v;
            a2 += w[2][4 * k4 + 0] * h0v; a3 += w[3][4 * k4 + 0] * h0v;
            a0 += w[0][4 * k4 + 1] * h1v; a1 += w[1][4 * k4 + 1] * h1v;
            a2 += w[2][4 * k4 + 1] * h1v; a3 += w[3][4 * k4 + 1] * h1v;
            a0 += w[0][4 * k4 + 2] * h2v; a1 += w[1][4 * k4 + 2] * h2v;
            a2 += w[2][4 * k4 + 2] * h2v; a3 += w[3][4 * k4 + 2] * h2v;
            a0 += w[0][4 * k4 + 3] * h3v; a1 += w[1][4 * k4 + 3] * h3v;
            a2 += w[2][4 * k4 + 3] * h3v; a3 += w[3][4 * k4 + 3] * h3v;
        }

        // gates + state update: all lane-local
        const float ig = sigm(a0);
        const float fg = sigm(a1);
        const float gg = tanh_f(a2);
        const float og = sigm(a3);
        c  = fg * c + ig * gg;
        hv = og * tanh_f(c);
        h_lds[bl][j] = hv;           // next iteration's reads see this (in-order DS)

        #pragma unroll
        for (int i = 0; i < II; ++i) xv[i] = xn[i];
    }

    // out[b] = dot(hT, W_lin) + b_lin  -- butterfly reduce within half-wave
    float p = hv * W_lin[j];
    p += __shfl_xor(p, 1);
    p += __shfl_xor(p, 2);
    p += __shfl_xor(p, 4);
    p += __shfl_xor(p, 8);
    p += __shfl_xor(p, 16);
    if (j == 0) out[b] = p + b_lin[0];
}

extern "C" void kernel_launch(void* const* d_in, const int* in_sizes, int n_in,
                              void* d_out, int out_size, void* d_ws, size_t ws_size,
                              hipStream_t stream) {
    const float* x     = (const float*)d_in[0];
    const float* h0    = (const float*)d_in[1];
    const float* c0    = (const float*)d_in[2];
    const float* W_ih  = (const float*)d_in[3];
    const float* W_hh  = (const float*)d_in[4];
    const float* b_ih  = (const float*)d_in[5];
    const float* b_hh  = (const float*)d_in[6];
    const float* W_lin = (const float*)d_in[7];
    const float* b_lin = (const float*)d_in[8];
    float* out = (float*)d_out;

    const int B = in_sizes[1] / HH;   // 4096
    dim3 grid(B / 8), block(256);
    lstm_fused<<<grid, block, 0, stream>>>(x, h0, c0, W_ih, W_hh, b_ih, b_hh, W_lin, b_lin, out);
}